// Round 9
// baseline (390.579 us; speedup 1.0000x reference)
//
#include <hip/hip_runtime.h>
#include <hip/hip_bf16.h>

typedef __attribute__((ext_vector_type(8))) short bf16x8;
typedef __attribute__((ext_vector_type(4))) float f32x4;
typedef __attribute__((ext_vector_type(16))) float f32x16;
typedef __attribute__((ext_vector_type(4))) int i32x4;
typedef __attribute__((ext_vector_type(8))) int i32x8;

constexpr int NB   = 8;
constexpr int CK   = 64;
constexpr int CVAL = 512;
constexpr int HW   = 4096;
constexpr int NT   = 128;
constexpr int CVT  = 256;

__device__ __forceinline__ unsigned short f2b(float f) {
  union { float f; unsigned u; } v; v.f = f;
  unsigned r = v.u + 0x7fffu + ((v.u >> 16) & 1u);   // RNE
  return (unsigned short)(r >> 16);
}
__device__ __forceinline__ float b2f(unsigned short b) {
  union { unsigned u; float f; } v; v.u = ((unsigned)b) << 16;
  return v.f;
}
// two ds_read_b128 straight into one 8-reg tuple (no shufflevector movs)
__device__ __forceinline__ i32x8 vread2(const char* vp, int o0, int o1) {
  union { i32x8 w; i32x4 h[2]; } u;
  u.h[0] = *(const i32x4*)(vp + o0);
  u.h[1] = *(const i32x4*)(vp + o1);
  return u.w;
}

#define GLDS16(g, l)                                                        \
  __builtin_amdgcn_global_load_lds(                                         \
      (const __attribute__((address_space(1))) unsigned int*)(g),           \
      (__attribute__((address_space(3))) unsigned int*)(l), 16, 0, 0)

// ---------------- prepass: transpose [b][c][m] f32 -> [b][m][c] bf16 ----------------
// swz=1: chunk j (8 shorts) stored at j^(m&7); also writes aq2 = (0.125*|a|^2+12)*log2e
__global__ __launch_bounds__(256) void prep_kt(
    const float* __restrict__ src, unsigned short* __restrict__ dst,
    float* __restrict__ aqout, int swz)
{
  int t = threadIdx.x;
  int m = blockIdx.x * 256 + t;
  int b = blockIdx.y;
  const float* s = src + (size_t)b * CK * HW + m;
  unsigned short* d = dst + ((size_t)b * HW + m) * CK;
  int xr = swz ? (m & 7) : 0;
  float sq = 0.f;
#pragma unroll
  for (int j = 0; j < 8; ++j) {
    unsigned short h[8];
#pragma unroll
    for (int e = 0; e < 8; ++e) {
      float x = s[(size_t)(j * 8 + e) * HW];
      sq += x * x;
      h[e] = f2b(x);
    }
    uint4 u;
    u.x = (unsigned)h[0] | ((unsigned)h[1] << 16);
    u.y = (unsigned)h[2] | ((unsigned)h[3] << 16);
    u.z = (unsigned)h[4] | ((unsigned)h[5] << 16);
    u.w = (unsigned)h[6] | ((unsigned)h[7] << 16);
    *(uint4*)(d + (j ^ xr) * 8) = u;
  }
  if (aqout)
    aqout[(size_t)b * HW + m] = (sq * 0.125f + 12.0f) * 1.4426950408889634f;
}

// ---------------- prepass: mv f32 -> fp8(e4m3) tile blobs for linear GLDS ----------------
__global__ __launch_bounds__(256) void prep_mv8(
    const float* __restrict__ src, unsigned char* __restrict__ dst)
{
  unsigned g = blockIdx.x * 256 + threadIdx.x;   // 16B chunk id
  unsigned tile = g >> 10;                       // (b*2+cvblk)*64 + t
  unsigned p16  = g & 1023;
  unsigned r128 = p16 >> 3;
  unsigned sl   = (p16 & 7) ^ (r128 & 7);        // unswizzled 16B slot in 128B row
  unsigned c7   = sl >> 2;
  unsigned mb   = (sl & 3) * 16;
  unsigned t    = tile & 63;
  unsigned row  = tile >> 6;                     // b*2 + cvblk
  const float* sp = src + ((size_t)(row * 256 + c7 * 128 + r128)) * HW + t * 64 + mb;
  unsigned u[4];
#pragma unroll
  for (int k = 0; k < 4; ++k) {
    float4 v = *(const float4*)(sp + k * 4);
    int lo8 = __builtin_amdgcn_cvt_pk_fp8_f32(v.x, v.y, 0, false);
    u[k] = (unsigned)__builtin_amdgcn_cvt_pk_fp8_f32(v.z, v.w, lo8, true);
  }
  *(uint4*)(dst + (size_t)tile * 16384 + p16 * 16) = make_uint4(u[0], u[1], u[2], u[3]);
}

// ---------------- hot kernel v9: v8 + VALU trims (vf-union, hoisted V, aAv, max3) ----------------
__global__ __launch_bounds__(256, 2) void mr_flash9(
    const unsigned short* __restrict__ kt,   // [B][4096][64] swizzled bf16
    const unsigned short* __restrict__ qt,   // [B][4096][64] plain bf16
    const unsigned char*  __restrict__ mvs8, // fp8 tile blobs (see prep_mv8)
    const float* __restrict__ aql,           // [B][4096] = (0.125*|a|^2+12)*log2e
    float* __restrict__ out)
{
  __shared__ __align__(16) unsigned short Kt[2][64][64];    // 16KB bf16 K
  __shared__ __align__(16) unsigned char  Vt[2][16384];     // 32KB fp8 V

  const int tid  = threadIdx.x;
  const int w    = tid >> 6;
  const int lane = tid & 63;
  const int hi   = lane >> 5;
  const int l5   = lane & 31;
  const int l7   = lane & 7;
  const int b    = blockIdx.z;
  const int cv0  = blockIdx.y * CVT;
  const int n0   = blockIdx.x * NT;

  const unsigned short* qB = qt + ((size_t)b * HW + n0) * CK;
  const unsigned short* kB = kt + (size_t)b * HW * CK;
  const unsigned char*  vT = mvs8 + (size_t)((b * 2 + blockIdx.y) * 64) * 16384;
  const float* aB = aql + (size_t)b * HW;

  // K LDS byte offsets (swizzled 16B chunk within a 128B row)
  int ab4[4];
#pragma unroll
  for (int j = 0; j < 4; ++j)
    ab4[j] = l5 * 128 + ((((2 * j + hi) ^ l7)) << 4);

#define KREAD(BUF, MT, KC) \
  (*(const bf16x8*)((const char*)Kt + (BUF) * 8192 + (MT) * 4096 + ab4[KC]))

  // V read bases: [c7][j] — lane reads row cv=(ct>>2)*128+(ct&3)*32+l5, k-half=hi
  int vb[2][2];
#pragma unroll
  for (int c7 = 0; c7 < 2; ++c7)
#pragma unroll
    for (int j = 0; j < 2; ++j)
      vb[c7][j] = l5 * 128 + ((c7 * 64 + hi * 32 + j * 16) ^ ((l5 & 7) << 4));

  // Q B-fragments, hoisted (col=n=l5, k = kc*16 + hi*8 + e)
  bf16x8 qf[4];
#pragma unroll
  for (int kc = 0; kc < 4; ++kc)
    qf[kc] = *(const bf16x8*)(qB + (size_t)(w * 32 + l5) * CK + kc * 16 + hi * 8);

  const f32x16 z16 = {0.f};
  f32x16 acc[8];
#pragma unroll
  for (int ct = 0; ct < 8; ++ct) acc[ct] = z16;
  float lrun = 0.f;

  // ---- prologue: stage tile 0 into buffer 0 ----
#pragma unroll
  for (int i = 0; i < 2; ++i) {
    int r = w * 16 + i * 8;
    GLDS16(kB + (size_t)r * CK + lane * 8, &Kt[0][r][0]);
  }
#pragma unroll
  for (int i = 0; i < 4; ++i) {
    int cb = i * 4096 + w * 1024;
    GLDS16(vT + cb + lane * 16, &Vt[0][cb]);
  }
  __syncthreads();

  constexpr float C_ = 0.36067376022224085f;  // 0.25 * log2(e)

#define QKCHAIN(BUF, MT, SREG)                                                 \
  __builtin_amdgcn_s_setprio(1);                                               \
  SREG = __builtin_amdgcn_mfma_f32_32x32x16_bf16(KREAD(BUF, MT, 0), qf[0], z16, 0, 0, 0); \
  SREG = __builtin_amdgcn_mfma_f32_32x32x16_bf16(KREAD(BUF, MT, 1), qf[1], SREG, 0, 0, 0); \
  SREG = __builtin_amdgcn_mfma_f32_32x32x16_bf16(KREAD(BUF, MT, 2), qf[2], SREG, 0, 0, 0); \
  SREG = __builtin_amdgcn_mfma_f32_32x32x16_bf16(KREAD(BUF, MT, 3), qf[3], SREG, 0, 0, 0); \
  __builtin_amdgcn_s_setprio(0);

// max of 16 via v_max3-friendly nested triples (exact: max is associative)
#define MAX16(A, DST)                                                          \
  {                                                                            \
    float x0 = fmaxf(fmaxf((A)[0], (A)[1]), (A)[2]);                           \
    float x1 = fmaxf(fmaxf((A)[3], (A)[4]), (A)[5]);                           \
    float x2 = fmaxf(fmaxf((A)[6], (A)[7]), (A)[8]);                           \
    float x3 = fmaxf(fmaxf((A)[9], (A)[10]), (A)[11]);                         \
    float x4 = fmaxf(fmaxf((A)[12], (A)[13]), (A)[14]);                        \
    DST = fmaxf(fmaxf(fmaxf(x0, x1), x2), fmaxf(fmaxf(x3, x4), (A)[15]));      \
  }

#define STEP(BUF, T, DOPF)                                                     \
  {                                                                            \
    const int m0_ = (T) * 64;                                                  \
    float aqa[16], aqb[16];                                                    \
    _Pragma("unroll") for (int j = 0; j < 4; ++j) {                            \
      float4 t0 = *(const float4*)(aB + m0_ + j * 8 + hi * 4);                 \
      float4 t1 = *(const float4*)(aB + m0_ + 32 + j * 8 + hi * 4);            \
      aqa[j * 4 + 0] = t0.x; aqa[j * 4 + 1] = t0.y;                            \
      aqa[j * 4 + 2] = t0.z; aqa[j * 4 + 3] = t0.w;                            \
      aqb[j * 4 + 0] = t1.x; aqb[j * 4 + 1] = t1.y;                            \
      aqb[j * 4 + 2] = t1.z; aqb[j * 4 + 3] = t1.w;                            \
    }                                                                          \
    if (DOPF) {                                                                \
      const int m1_ = m0_ + 64;                                                \
      _Pragma("unroll") for (int i = 0; i < 2; ++i) {                          \
        int r = w * 16 + i * 8;                                                \
        GLDS16(kB + (size_t)(m1_ + r) * CK + lane * 8, &Kt[(BUF) ^ 1][r][0]);  \
      }                                                                        \
      _Pragma("unroll") for (int i = 0; i < 4; ++i) {                          \
        int cb = i * 4096 + w * 1024;                                          \
        GLDS16(vT + (size_t)((T) + 1) * 16384 + cb + lane * 16,                \
               &Vt[(BUF) ^ 1][cb]);                                            \
      }                                                                        \
    }                                                                          \
    f32x16 sA;                                                                 \
    QKCHAIN(BUF, 0, sA)                                                        \
    float aAv[16];                                                             \
    _Pragma("unroll") for (int r = 0; r < 16; ++r)                             \
      aAv[r] = fmaf(sA[r], C_, -aqa[r]);                                       \
    float mA; MAX16(aAv, mA)                                                   \
    f32x16 sB;                                                                 \
    QKCHAIN(BUF, 1, sB)                                                        \
    /* hoist all V reads for PV: land directly in 8-reg tuples, latency hides  \
       under the softmax VALU below; PV is then pure-register */               \
    i32x8 vreg[8];                                                             \
    { const char* vp0 = (const char*)Vt + (BUF) * 16384;                       \
      _Pragma("unroll") for (int ct = 0; ct < 8; ++ct)                         \
        vreg[ct] = vread2(vp0 + (ct & 3) * 4096, vb[ct >> 2][0], vb[ct >> 2][1]); } \
    float aBv[16];                                                             \
    _Pragma("unroll") for (int r = 0; r < 16; ++r)                             \
      aBv[r] = fmaf(sB[r], C_, -aqb[r]);                                       \
    float mB; MAX16(aBv, mB)                                                   \
    float m2 = fmaxf(mA, mB);                                                  \
    auto mr_ = __builtin_amdgcn_permlane32_swap(__float_as_int(m2),            \
                                                __float_as_int(m2), false, false); \
    float cm = fmaxf(__int_as_float(mr_[0]), __int_as_float(mr_[1]));          \
    int e_ = (int)floorf(cm) - 3;                                              \
    e_ = e_ < -120 ? -120 : e_;                                                \
    float ef_ = (float)e_;                                                     \
    float tsum = 0.f;                                                          \
    unsigned uA[4], uB2[4];                                                    \
    _Pragma("unroll") for (int g = 0; g < 4; ++g) {                            \
      float p0 = __builtin_amdgcn_exp2f(aAv[4 * g + 0] - ef_);                 \
      float p1 = __builtin_amdgcn_exp2f(aAv[4 * g + 1] - ef_);                 \
      float p2 = __builtin_amdgcn_exp2f(aAv[4 * g + 2] - ef_);                 \
      float p3 = __builtin_amdgcn_exp2f(aAv[4 * g + 3] - ef_);                 \
      tsum += (p0 + p1) + (p2 + p3);                                           \
      int lo8 = __builtin_amdgcn_cvt_pk_fp8_f32(p0, p1, 0, false);             \
      uA[g] = (unsigned)__builtin_amdgcn_cvt_pk_fp8_f32(p2, p3, lo8, true);    \
    }                                                                          \
    _Pragma("unroll") for (int g = 0; g < 4; ++g) {                            \
      float p0 = __builtin_amdgcn_exp2f(aBv[4 * g + 0] - ef_);                 \
      float p1 = __builtin_amdgcn_exp2f(aBv[4 * g + 1] - ef_);                 \
      float p2 = __builtin_amdgcn_exp2f(aBv[4 * g + 2] - ef_);                 \
      float p3 = __builtin_amdgcn_exp2f(aBv[4 * g + 3] - ef_);                 \
      tsum += (p0 + p1) + (p2 + p3);                                           \
      int lo8 = __builtin_amdgcn_cvt_pk_fp8_f32(p0, p1, 0, false);             \
      uB2[g] = (unsigned)__builtin_amdgcn_cvt_pk_fp8_f32(p2, p3, lo8, true);   \
    }                                                                          \
    lrun += ldexpf(tsum, e_);                                                  \
    i32x8 pw;                                                                  \
    { auto s_ = __builtin_amdgcn_permlane32_swap((int)uA[0], (int)uB2[0], false, false); pw[0] = s_[0]; pw[1] = s_[1]; } \
    { auto s_ = __builtin_amdgcn_permlane32_swap((int)uA[1], (int)uB2[1], false, false); pw[2] = s_[0]; pw[3] = s_[1]; } \
    { auto s_ = __builtin_amdgcn_permlane32_swap((int)uA[2], (int)uB2[2], false, false); pw[4] = s_[0]; pw[5] = s_[1]; } \
    { auto s_ = __builtin_amdgcn_permlane32_swap((int)uA[3], (int)uB2[3], false, false); pw[6] = s_[0]; pw[7] = s_[1]; } \
    int sp_ = (e_ + 127) * 0x01010101;  /* replicate E8M0 byte: opsel-proof */ \
    __builtin_amdgcn_s_setprio(1);                                             \
    _Pragma("unroll") for (int ct = 0; ct < 8; ++ct) {                         \
      acc[ct] = __builtin_amdgcn_mfma_scale_f32_32x32x64_f8f6f4(               \
          vreg[ct], pw, acc[ct], 0, 0, 0, 0x7F7F7F7F, 0, sp_);                 \
    }                                                                          \
    __builtin_amdgcn_s_setprio(0);                                             \
    __syncthreads();                                                           \
  }

  for (int t2 = 0; t2 < 32; ++t2) {
    STEP(0, 2 * t2, true)
    STEP(1, 2 * t2 + 1, (t2 < 31))
  }

  // ---- epilogue: full column sum across halves, normalize, store ----
  lrun += __shfl_xor(lrun, 32);
  float rl = 1.f / lrun;
  int n = n0 + w * 32 + l5;
#pragma unroll
  for (int ct = 0; ct < 8; ++ct) {
#pragma unroll
    for (int r = 0; r < 16; ++r) {
      int ch = cv0 + ct * 32 + (r & 3) + 8 * (r >> 2) + 4 * hi;
      out[((size_t)b * 1024 + ch) * HW + n] = acc[ct][r] * rl;
    }
  }
#undef KREAD
#undef QKCHAIN
#undef MAX16
#undef STEP
}

// ---------------- fallback (used only if ws too small): naive-correct path ----------------
__global__ __launch_bounds__(256) void mr_flash(
    const float* __restrict__ mk, const float* __restrict__ qk,
    const float* __restrict__ mv, float* __restrict__ out)
{
  __shared__ __align__(16) unsigned short Kt[32][72];
  __shared__ __align__(16) union {
    unsigned short Qt[NT][72];
    unsigned short Vt[128][40];
  } U;
  __shared__ __align__(16) unsigned short Pl[4][32][40];
  __shared__ __align__(16) float asq[32];

  const int tid  = threadIdx.x;
  const int w    = tid >> 6;
  const int lane = tid & 63;
  const int q    = lane >> 4;
  const int ln   = lane & 15;
  const int b    = blockIdx.z;
  const int cv0  = blockIdx.y * 128;
  const int n0   = blockIdx.x * NT;

  const float* mkB = mk + (size_t)b * CK * HW;
  const float* qkB = qk + (size_t)b * CK * HW;
  const float* mvB = mv + ((size_t)b * CVAL + cv0) * HW;

#pragma unroll
  for (int i = 0; i < 8; ++i) {
    int f = i * 256 + tid;
    int c = f >> 5;
    int nq = f & 31;
    float4 v = *(const float4*)(qkB + (size_t)c * HW + (n0 + nq * 4));
    U.Qt[nq * 4 + 0][c] = f2b(v.x);
    U.Qt[nq * 4 + 1][c] = f2b(v.y);
    U.Qt[nq * 4 + 2][c] = f2b(v.z);
    U.Qt[nq * 4 + 3][c] = f2b(v.w);
  }
  __syncthreads();

  bf16x8 qf[2][2];
#pragma unroll
  for (int nt = 0; nt < 2; ++nt)
#pragma unroll
    for (int cs = 0; cs < 2; ++cs)
      qf[nt][cs] = *(const bf16x8*)&U.Qt[w * 32 + nt * 16 + ln][cs * 32 + q * 8];

  f32x4 acc[8][2];
#pragma unroll
  for (int ct = 0; ct < 8; ++ct)
#pragma unroll
    for (int nt = 0; nt < 2; ++nt)
      acc[ct][nt] = f32x4{0.f, 0.f, 0.f, 0.f};

  float mrun[2] = {-INFINITY, -INFINITY};
  float lrun[2] = {0.f, 0.f};

  for (int m0 = 0; m0 < HW; m0 += 32) {
    __syncthreads();
#pragma unroll
    for (int i = 0; i < 2; ++i) {
      int f = i * 256 + tid;
      int c = f >> 3;
      int mq = f & 7;
      float4 v = *(const float4*)(mkB + (size_t)c * HW + (m0 + mq * 4));
      Kt[mq * 4 + 0][c] = f2b(v.x);
      Kt[mq * 4 + 1][c] = f2b(v.y);
      Kt[mq * 4 + 2][c] = f2b(v.z);
      Kt[mq * 4 + 3][c] = f2b(v.w);
    }
#pragma unroll
    for (int i = 0; i < 4; ++i) {
      int f = i * 256 + tid;
      int cvr = f >> 3;
      int mq = f & 7;
      float4 v = *(const float4*)(mvB + (size_t)cvr * HW + (m0 + mq * 4));
      unsigned lo = (unsigned)f2b(v.x) | ((unsigned)f2b(v.y) << 16);
      unsigned hi2 = (unsigned)f2b(v.z) | ((unsigned)f2b(v.w) << 16);
      *(uint2*)&U.Vt[cvr][mq * 4] = make_uint2(lo, hi2);
    }
    __syncthreads();

    if (tid < 128) {
      int m = tid >> 2;
      int c0 = (tid & 3) * 16;
      bf16x8 a0 = *(const bf16x8*)&Kt[m][c0];
      bf16x8 a1 = *(const bf16x8*)&Kt[m][c0 + 8];
      float s = 0.f;
#pragma unroll
      for (int e = 0; e < 8; ++e) {
        float x = b2f((unsigned short)a0[e]);
        float y = b2f((unsigned short)a1[e]);
        s += x * x + y * y;
      }
      s += __shfl_xor(s, 1);
      s += __shfl_xor(s, 2);
      if ((tid & 3) == 0) asq[m] = s;
    }
    __syncthreads();

    bf16x8 af[2][2];
#pragma unroll
    for (int mt = 0; mt < 2; ++mt)
#pragma unroll
      for (int cs = 0; cs < 2; ++cs)
        af[mt][cs] = *(const bf16x8*)&Kt[mt * 16 + ln][cs * 32 + q * 8];

    float sv[2][2][4];
#pragma unroll
    for (int mt = 0; mt < 2; ++mt) {
      float4 aq = *(const float4*)&asq[mt * 16 + q * 4];
#pragma unroll
      for (int nt = 0; nt < 2; ++nt) {
        f32x4 d = {0.f, 0.f, 0.f, 0.f};
        d = __builtin_amdgcn_mfma_f32_16x16x32_bf16(af[mt][0], qf[nt][0], d, 0, 0, 0);
        d = __builtin_amdgcn_mfma_f32_16x16x32_bf16(af[mt][1], qf[nt][1], d, 0, 0, 0);
        sv[mt][nt][0] = (2.f * d[0] - aq.x) * 0.125f;
        sv[mt][nt][1] = (2.f * d[1] - aq.y) * 0.125f;
        sv[mt][nt][2] = (2.f * d[2] - aq.z) * 0.125f;
        sv[mt][nt][3] = (2.f * d[3] - aq.w) * 0.125f;
      }
    }

#pragma unroll
    for (int nt = 0; nt < 2; ++nt) {
      float tm = sv[0][nt][0];
#pragma unroll
      for (int mt = 0; mt < 2; ++mt)
#pragma unroll
        for (int r = 0; r < 4; ++r) tm = fmaxf(tm, sv[mt][nt][r]);
      tm = fmaxf(tm, __shfl_xor(tm, 16));
      tm = fmaxf(tm, __shfl_xor(tm, 32));
      float mnew = fmaxf(mrun[nt], tm);
      float sc = __expf(mrun[nt] - mnew);
      float ts = 0.f;
      unsigned short pb[2][4];
#pragma unroll
      for (int mt = 0; mt < 2; ++mt)
#pragma unroll
        for (int r = 0; r < 4; ++r) {
          float p = __expf(sv[mt][nt][r] - mnew);
          ts += p;
          pb[mt][r] = f2b(p);
        }
      ts += __shfl_xor(ts, 16);
      ts += __shfl_xor(ts, 32);
      lrun[nt] = lrun[nt] * sc + ts;
      mrun[nt] = mnew;
#pragma unroll
      for (int ct = 0; ct < 8; ++ct) {
        acc[ct][nt][0] *= sc; acc[ct][nt][1] *= sc;
        acc[ct][nt][2] *= sc; acc[ct][nt][3] *= sc;
      }
#pragma unroll
      for (int mt = 0; mt < 2; ++mt) {
        unsigned lo = (unsigned)pb[mt][0] | ((unsigned)pb[mt][1] << 16);
        unsigned hi2 = (unsigned)pb[mt][2] | ((unsigned)pb[mt][3] << 16);
        *(uint2*)&Pl[w][nt * 16 + ln][mt * 16 + q * 4] = make_uint2(lo, hi2);
      }
    }

    bf16x8 pf[2];
    pf[0] = *(const bf16x8*)&Pl[w][ln][q * 8];
    pf[1] = *(const bf16x8*)&Pl[w][16 + ln][q * 8];
#pragma unroll
    for (int ct = 0; ct < 8; ++ct) {
      bf16x8 vf = *(const bf16x8*)&U.Vt[ct * 16 + ln][q * 8];
      acc[ct][0] = __builtin_amdgcn_mfma_f32_16x16x32_bf16(vf, pf[0], acc[ct][0], 0, 0, 0);
      acc[ct][1] = __builtin_amdgcn_mfma_f32_16x16x32_bf16(vf, pf[1], acc[ct][1], 0, 0, 0);
    }
  }

#pragma unroll
  for (int nt = 0; nt < 2; ++nt) {
    float rl = 1.f / lrun[nt];
    int n = n0 + w * 32 + nt * 16 + ln;
#pragma unroll
    for (int ct = 0; ct < 8; ++ct) {
#pragma unroll
      for (int r = 0; r < 4; ++r) {
        int ch = cv0 + ct * 16 + q * 4 + r;
        out[((size_t)b * 1024 + ch) * HW + n] = acc[ct][nt][r] * rl;
      }
    }
  }
}

// concat tail: out[:, 512:1024, :, :] = qv
__global__ void qv_copy(const float4* __restrict__ qv, float4* __restrict__ out)
{
  size_t i = (size_t)blockIdx.x * blockDim.x + threadIdx.x;
  constexpr size_t TOT = (size_t)NB * CVAL * (HW / 4);
  if (i >= TOT) return;
  size_t n4  = i & (HW / 4 - 1);
  size_t cvb = i >> 10;
  size_t b   = cvb >> 9;
  size_t cv  = cvb & 511;
  out[((b * 1024) + 512 + cv) * (HW / 4) + n4] = qv[i];
}

extern "C" void kernel_launch(void* const* d_in, const int* in_sizes, int n_in,
                              void* d_out, int out_size, void* d_ws, size_t ws_size,
                              hipStream_t stream) {
  const float* mk = (const float*)d_in[0];
  const float* qk = (const float*)d_in[1];
  const float* mv = (const float*)d_in[2];
  const float* qv = (const float*)d_in[3];
  float* out = (float*)d_out;

  constexpr size_t KT   = (size_t)NB * HW * CK;            // ushort elems
  constexpr size_t MV8  = (size_t)NB * CVAL * HW;          // fp8 bytes
  constexpr size_t ASQ  = (size_t)NB * HW;
  constexpr size_t NEED = KT * 2 * 2 + MV8 + ASQ * 4;

  if (ws_size >= NEED) {
    unsigned short* kt  = (unsigned short*)d_ws;
    unsigned short* qtp = kt + KT;
    unsigned char*  mvs = (unsigned char*)(qtp + KT);
    float* aq = (float*)(mvs + MV8);
    prep_kt<<<dim3(HW / 256, NB), 256, 0, stream>>>(mk, kt, aq, 1);
    prep_kt<<<dim3(HW / 256, NB), 256, 0, stream>>>(qk, qtp, nullptr, 0);
    prep_mv8<<<(NB * 2 * 64 * 1024) / 256, 256, 0, stream>>>(mv, mvs);
    mr_flash9<<<dim3(HW / NT, CVAL / CVT, NB), 256, 0, stream>>>(kt, qtp, mvs, aq, out);
  } else {
    mr_flash<<<dim3(HW / NT, CVAL / 128, NB), 256, 0, stream>>>(mk, qk, mv, out);
  }

  constexpr int NCPY = NB * CVAL * (HW / 4);
  qv_copy<<<(NCPY + 255) / 256, 256, 0, stream>>>((const float4*)qv, (float4*)out);
}

// Round 10
// 189.765 us; speedup vs baseline: 2.0582x; 2.0582x over previous
//
#include <hip/hip_runtime.h>
#include <hip/hip_bf16.h>

typedef __attribute__((ext_vector_type(8))) short bf16x8;
typedef __attribute__((ext_vector_type(4))) float f32x4;
typedef __attribute__((ext_vector_type(16))) float f32x16;
typedef __attribute__((ext_vector_type(4))) int i32x4;
typedef __attribute__((ext_vector_type(8))) int i32x8;

constexpr int NB   = 8;
constexpr int CK   = 64;
constexpr int CVAL = 512;
constexpr int HW   = 4096;
constexpr int NT   = 128;
constexpr int CVT  = 256;

__device__ __forceinline__ unsigned short f2b(float f) {
  union { float f; unsigned u; } v; v.f = f;
  unsigned r = v.u + 0x7fffu + ((v.u >> 16) & 1u);   // RNE
  return (unsigned short)(r >> 16);
}
__device__ __forceinline__ float b2f(unsigned short b) {
  union { unsigned u; float f; } v; v.u = ((unsigned)b) << 16;
  return v.f;
}
// two ds_read_b128 straight into one 8-reg tuple (no shufflevector movs)
__device__ __forceinline__ i32x8 vread2(const char* vp, int o0, int o1) {
  union { i32x8 w; i32x4 h[2]; } u;
  u.h[0] = *(const i32x4*)(vp + o0);
  u.h[1] = *(const i32x4*)(vp + o1);
  return u.w;
}

#define GLDS16(g, l)                                                        \
  __builtin_amdgcn_global_load_lds(                                         \
      (const __attribute__((address_space(1))) unsigned int*)(g),           \
      (__attribute__((address_space(3))) unsigned int*)(l), 16, 0, 0)

// ---------------- prepass: transpose [b][c][m] f32 -> [b][m][c] bf16 ----------------
// swz=1: chunk j (8 shorts) stored at j^(m&7); also writes aq2 = (0.125*|a|^2+12)*log2e
__global__ __launch_bounds__(256) void prep_kt(
    const float* __restrict__ src, unsigned short* __restrict__ dst,
    float* __restrict__ aqout, int swz)
{
  int t = threadIdx.x;
  int m = blockIdx.x * 256 + t;
  int b = blockIdx.y;
  const float* s = src + (size_t)b * CK * HW + m;
  unsigned short* d = dst + ((size_t)b * HW + m) * CK;
  int xr = swz ? (m & 7) : 0;
  float sq = 0.f;
#pragma unroll
  for (int j = 0; j < 8; ++j) {
    unsigned short h[8];
#pragma unroll
    for (int e = 0; e < 8; ++e) {
      float x = s[(size_t)(j * 8 + e) * HW];
      sq += x * x;
      h[e] = f2b(x);
    }
    uint4 u;
    u.x = (unsigned)h[0] | ((unsigned)h[1] << 16);
    u.y = (unsigned)h[2] | ((unsigned)h[3] << 16);
    u.z = (unsigned)h[4] | ((unsigned)h[5] << 16);
    u.w = (unsigned)h[6] | ((unsigned)h[7] << 16);
    *(uint4*)(d + (j ^ xr) * 8) = u;
  }
  if (aqout)
    aqout[(size_t)b * HW + m] = (sq * 0.125f + 12.0f) * 1.4426950408889634f;
}

// ---------------- prepass: mv f32 -> fp8(e4m3) tile blobs for linear GLDS ----------------
__global__ __launch_bounds__(256) void prep_mv8(
    const float* __restrict__ src, unsigned char* __restrict__ dst)
{
  unsigned g = blockIdx.x * 256 + threadIdx.x;   // 16B chunk id
  unsigned tile = g >> 10;                       // (b*2+cvblk)*64 + t
  unsigned p16  = g & 1023;
  unsigned r128 = p16 >> 3;
  unsigned sl   = (p16 & 7) ^ (r128 & 7);        // unswizzled 16B slot in 128B row
  unsigned c7   = sl >> 2;
  unsigned mb   = (sl & 3) * 16;
  unsigned t    = tile & 63;
  unsigned row  = tile >> 6;                     // b*2 + cvblk
  const float* sp = src + ((size_t)(row * 256 + c7 * 128 + r128)) * HW + t * 64 + mb;
  unsigned u[4];
#pragma unroll
  for (int k = 0; k < 4; ++k) {
    float4 v = *(const float4*)(sp + k * 4);
    int lo8 = __builtin_amdgcn_cvt_pk_fp8_f32(v.x, v.y, 0, false);
    u[k] = (unsigned)__builtin_amdgcn_cvt_pk_fp8_f32(v.z, v.w, lo8, true);
  }
  *(uint4*)(dst + (size_t)tile * 16384 + p16 * 16) = make_uint4(u[0], u[1], u[2], u[3]);
}

// ---------------- hot kernel v10: v8 + register-safe VALU trims ----------------
__global__ __launch_bounds__(256, 2) void mr_flash10(
    const unsigned short* __restrict__ kt,   // [B][4096][64] swizzled bf16
    const unsigned short* __restrict__ qt,   // [B][4096][64] plain bf16
    const unsigned char*  __restrict__ mvs8, // fp8 tile blobs (see prep_mv8)
    const float* __restrict__ aql,           // [B][4096] = (0.125*|a|^2+12)*log2e
    float* __restrict__ out)
{
  __shared__ __align__(16) unsigned short Kt[2][64][64];    // 16KB bf16 K
  __shared__ __align__(16) unsigned char  Vt[2][16384];     // 32KB fp8 V

  const int tid  = threadIdx.x;
  const int w    = tid >> 6;
  const int lane = tid & 63;
  const int hi   = lane >> 5;
  const int l5   = lane & 31;
  const int l7   = lane & 7;
  const int b    = blockIdx.z;
  const int cv0  = blockIdx.y * CVT;
  const int n0   = blockIdx.x * NT;

  const unsigned short* qB = qt + ((size_t)b * HW + n0) * CK;
  const unsigned short* kB = kt + (size_t)b * HW * CK;
  const unsigned char*  vT = mvs8 + (size_t)((b * 2 + blockIdx.y) * 64) * 16384;
  const float* aB = aql + (size_t)b * HW;

  // K LDS byte offsets (swizzled 16B chunk within a 128B row)
  int ab4[4];
#pragma unroll
  for (int j = 0; j < 4; ++j)
    ab4[j] = l5 * 128 + ((((2 * j + hi) ^ l7)) << 4);

#define KREAD(BUF, MT, KC) \
  (*(const bf16x8*)((const char*)Kt + (BUF) * 8192 + (MT) * 4096 + ab4[KC]))

  // V read bases: [c7][j] — lane reads row cv=(ct>>2)*128+(ct&3)*32+l5, k-half=hi
  int vb[2][2];
#pragma unroll
  for (int c7 = 0; c7 < 2; ++c7)
#pragma unroll
    for (int j = 0; j < 2; ++j)
      vb[c7][j] = l5 * 128 + ((c7 * 64 + hi * 32 + j * 16) ^ ((l5 & 7) << 4));

  // Q B-fragments, hoisted (col=n=l5, k = kc*16 + hi*8 + e)
  bf16x8 qf[4];
#pragma unroll
  for (int kc = 0; kc < 4; ++kc)
    qf[kc] = *(const bf16x8*)(qB + (size_t)(w * 32 + l5) * CK + kc * 16 + hi * 8);

  const f32x16 z16 = {0.f};
  f32x16 acc[8];
#pragma unroll
  for (int ct = 0; ct < 8; ++ct) acc[ct] = z16;
  float lrun = 0.f;

  // ---- prologue: stage tile 0 into buffer 0 ----
#pragma unroll
  for (int i = 0; i < 2; ++i) {
    int r = w * 16 + i * 8;
    GLDS16(kB + (size_t)r * CK + lane * 8, &Kt[0][r][0]);
  }
#pragma unroll
  for (int i = 0; i < 4; ++i) {
    int cb = i * 4096 + w * 1024;
    GLDS16(vT + cb + lane * 16, &Vt[0][cb]);
  }
  __syncthreads();

  constexpr float C_ = 0.36067376022224085f;  // 0.25 * log2(e)

#define QKCHAIN(BUF, MT, SREG)                                                 \
  __builtin_amdgcn_s_setprio(1);                                               \
  SREG = __builtin_amdgcn_mfma_f32_32x32x16_bf16(KREAD(BUF, MT, 0), qf[0], z16, 0, 0, 0); \
  SREG = __builtin_amdgcn_mfma_f32_32x32x16_bf16(KREAD(BUF, MT, 1), qf[1], SREG, 0, 0, 0); \
  SREG = __builtin_amdgcn_mfma_f32_32x32x16_bf16(KREAD(BUF, MT, 2), qf[2], SREG, 0, 0, 0); \
  SREG = __builtin_amdgcn_mfma_f32_32x32x16_bf16(KREAD(BUF, MT, 3), qf[3], SREG, 0, 0, 0); \
  __builtin_amdgcn_s_setprio(0);

// max of 16 via v_max3-friendly nested triples (exact: max is associative)
#define MAX16(A, DST)                                                          \
  {                                                                            \
    float x0 = fmaxf(fmaxf((A)[0], (A)[1]), (A)[2]);                           \
    float x1 = fmaxf(fmaxf((A)[3], (A)[4]), (A)[5]);                           \
    float x2 = fmaxf(fmaxf((A)[6], (A)[7]), (A)[8]);                           \
    float x3 = fmaxf(fmaxf((A)[9], (A)[10]), (A)[11]);                         \
    float x4 = fmaxf(fmaxf((A)[12], (A)[13]), (A)[14]);                        \
    DST = fmaxf(fmaxf(fmaxf(x0, x1), x2), fmaxf(fmaxf(x3, x4), (A)[15]));      \
  }

#define STEP(BUF, T, DOPF)                                                     \
  {                                                                            \
    const int m0_ = (T) * 64;                                                  \
    float aqa[16], aqb[16];                                                    \
    _Pragma("unroll") for (int j = 0; j < 4; ++j) {                            \
      float4 t0 = *(const float4*)(aB + m0_ + j * 8 + hi * 4);                 \
      float4 t1 = *(const float4*)(aB + m0_ + 32 + j * 8 + hi * 4);            \
      aqa[j * 4 + 0] = t0.x; aqa[j * 4 + 1] = t0.y;                            \
      aqa[j * 4 + 2] = t0.z; aqa[j * 4 + 3] = t0.w;                            \
      aqb[j * 4 + 0] = t1.x; aqb[j * 4 + 1] = t1.y;                            \
      aqb[j * 4 + 2] = t1.z; aqb[j * 4 + 3] = t1.w;                            \
    }                                                                          \
    if (DOPF) {                                                                \
      const int m1_ = m0_ + 64;                                                \
      _Pragma("unroll") for (int i = 0; i < 2; ++i) {                          \
        int r = w * 16 + i * 8;                                                \
        GLDS16(kB + (size_t)(m1_ + r) * CK + lane * 8, &Kt[(BUF) ^ 1][r][0]);  \
      }                                                                        \
      _Pragma("unroll") for (int i = 0; i < 4; ++i) {                          \
        int cb = i * 4096 + w * 1024;                                          \
        GLDS16(vT + (size_t)((T) + 1) * 16384 + cb + lane * 16,                \
               &Vt[(BUF) ^ 1][cb]);                                            \
      }                                                                        \
    }                                                                          \
    f32x16 sA;                                                                 \
    QKCHAIN(BUF, 0, sA)                                                        \
    float aAv[16];                                                             \
    _Pragma("unroll") for (int r = 0; r < 16; ++r)                             \
      aAv[r] = fmaf(sA[r], C_, -aqa[r]);                                       \
    float mA; MAX16(aAv, mA)                                                   \
    f32x16 sB;                                                                 \
    QKCHAIN(BUF, 1, sB)                                                        \
    float aBv[16];                                                             \
    _Pragma("unroll") for (int r = 0; r < 16; ++r)                             \
      aBv[r] = fmaf(sB[r], C_, -aqb[r]);                                       \
    float mB; MAX16(aBv, mB)                                                   \
    float m2 = fmaxf(mA, mB);                                                  \
    auto mr_ = __builtin_amdgcn_permlane32_swap(__float_as_int(m2),            \
                                                __float_as_int(m2), false, false); \
    float cm = fmaxf(__int_as_float(mr_[0]), __int_as_float(mr_[1]));          \
    int e_ = (int)floorf(cm) - 3;                                              \
    e_ = e_ < -120 ? -120 : e_;                                                \
    float ef_ = (float)e_;                                                     \
    float tsum = 0.f;                                                          \
    unsigned uA[4], uB2[4];                                                    \
    _Pragma("unroll") for (int g = 0; g < 4; ++g) {                            \
      float p0 = __builtin_amdgcn_exp2f(aAv[4 * g + 0] - ef_);                 \
      float p1 = __builtin_amdgcn_exp2f(aAv[4 * g + 1] - ef_);                 \
      float p2 = __builtin_amdgcn_exp2f(aAv[4 * g + 2] - ef_);                 \
      float p3 = __builtin_amdgcn_exp2f(aAv[4 * g + 3] - ef_);                 \
      tsum += (p0 + p1) + (p2 + p3);                                           \
      int lo8 = __builtin_amdgcn_cvt_pk_fp8_f32(p0, p1, 0, false);             \
      uA[g] = (unsigned)__builtin_amdgcn_cvt_pk_fp8_f32(p2, p3, lo8, true);    \
    }                                                                          \
    _Pragma("unroll") for (int g = 0; g < 4; ++g) {                            \
      float p0 = __builtin_amdgcn_exp2f(aBv[4 * g + 0] - ef_);                 \
      float p1 = __builtin_amdgcn_exp2f(aBv[4 * g + 1] - ef_);                 \
      float p2 = __builtin_amdgcn_exp2f(aBv[4 * g + 2] - ef_);                 \
      float p3 = __builtin_amdgcn_exp2f(aBv[4 * g + 3] - ef_);                 \
      tsum += (p0 + p1) + (p2 + p3);                                           \
      int lo8 = __builtin_amdgcn_cvt_pk_fp8_f32(p0, p1, 0, false);             \
      uB2[g] = (unsigned)__builtin_amdgcn_cvt_pk_fp8_f32(p2, p3, lo8, true);   \
    }                                                                          \
    lrun += ldexpf(tsum, e_);                                                  \
    i32x8 pw;                                                                  \
    { auto s_ = __builtin_amdgcn_permlane32_swap((int)uA[0], (int)uB2[0], false, false); pw[0] = s_[0]; pw[1] = s_[1]; } \
    { auto s_ = __builtin_amdgcn_permlane32_swap((int)uA[1], (int)uB2[1], false, false); pw[2] = s_[0]; pw[3] = s_[1]; } \
    { auto s_ = __builtin_amdgcn_permlane32_swap((int)uA[2], (int)uB2[2], false, false); pw[4] = s_[0]; pw[5] = s_[1]; } \
    { auto s_ = __builtin_amdgcn_permlane32_swap((int)uA[3], (int)uB2[3], false, false); pw[6] = s_[0]; pw[7] = s_[1]; } \
    int sp_ = (e_ + 127) * 0x01010101;  /* replicate E8M0 byte: opsel-proof */ \
    __builtin_amdgcn_s_setprio(1);                                             \
    _Pragma("unroll") for (int ct = 0; ct < 8; ++ct) {                         \
      const char* vp = (const char*)Vt + (BUF) * 16384 + (ct & 3) * 4096;      \
      i32x8 vf = vread2(vp, vb[ct >> 2][0], vb[ct >> 2][1]);                   \
      acc[ct] = __builtin_amdgcn_mfma_scale_f32_32x32x64_f8f6f4(               \
          vf, pw, acc[ct], 0, 0, 0, 0x7F7F7F7F, 0, sp_);                       \
    }                                                                          \
    __builtin_amdgcn_s_setprio(0);                                             \
    __syncthreads();                                                           \
  }

  for (int t2 = 0; t2 < 32; ++t2) {
    STEP(0, 2 * t2, true)
    STEP(1, 2 * t2 + 1, (t2 < 31))
  }

  // ---- epilogue: full column sum across halves, normalize, store ----
  lrun += __shfl_xor(lrun, 32);
  float rl = 1.f / lrun;
  int n = n0 + w * 32 + l5;
#pragma unroll
  for (int ct = 0; ct < 8; ++ct) {
#pragma unroll
    for (int r = 0; r < 16; ++r) {
      int ch = cv0 + ct * 32 + (r & 3) + 8 * (r >> 2) + 4 * hi;
      out[((size_t)b * 1024 + ch) * HW + n] = acc[ct][r] * rl;
    }
  }
#undef KREAD
#undef QKCHAIN
#undef MAX16
#undef STEP
}

// ---------------- fallback (used only if ws too small): naive-correct path ----------------
__global__ __launch_bounds__(256) void mr_flash(
    const float* __restrict__ mk, const float* __restrict__ qk,
    const float* __restrict__ mv, float* __restrict__ out)
{
  __shared__ __align__(16) unsigned short Kt[32][72];
  __shared__ __align__(16) union {
    unsigned short Qt[NT][72];
    unsigned short Vt[128][40];
  } U;
  __shared__ __align__(16) unsigned short Pl[4][32][40];
  __shared__ __align__(16) float asq[32];

  const int tid  = threadIdx.x;
  const int w    = tid >> 6;
  const int lane = tid & 63;
  const int q    = lane >> 4;
  const int ln   = lane & 15;
  const int b    = blockIdx.z;
  const int cv0  = blockIdx.y * 128;
  const int n0   = blockIdx.x * NT;

  const float* mkB = mk + (size_t)b * CK * HW;
  const float* qkB = qk + (size_t)b * CK * HW;
  const float* mvB = mv + ((size_t)b * CVAL + cv0) * HW;

#pragma unroll
  for (int i = 0; i < 8; ++i) {
    int f = i * 256 + tid;
    int c = f >> 5;
    int nq = f & 31;
    float4 v = *(const float4*)(qkB + (size_t)c * HW + (n0 + nq * 4));
    U.Qt[nq * 4 + 0][c] = f2b(v.x);
    U.Qt[nq * 4 + 1][c] = f2b(v.y);
    U.Qt[nq * 4 + 2][c] = f2b(v.z);
    U.Qt[nq * 4 + 3][c] = f2b(v.w);
  }
  __syncthreads();

  bf16x8 qf[2][2];
#pragma unroll
  for (int nt = 0; nt < 2; ++nt)
#pragma unroll
    for (int cs = 0; cs < 2; ++cs)
      qf[nt][cs] = *(const bf16x8*)&U.Qt[w * 32 + nt * 16 + ln][cs * 32 + q * 8];

  f32x4 acc[8][2];
#pragma unroll
  for (int ct = 0; ct < 8; ++ct)
#pragma unroll
    for (int nt = 0; nt < 2; ++nt)
      acc[ct][nt] = f32x4{0.f, 0.f, 0.f, 0.f};

  float mrun[2] = {-INFINITY, -INFINITY};
  float lrun[2] = {0.f, 0.f};

  for (int m0 = 0; m0 < HW; m0 += 32) {
    __syncthreads();
#pragma unroll
    for (int i = 0; i < 2; ++i) {
      int f = i * 256 + tid;
      int c = f >> 3;
      int mq = f & 7;
      float4 v = *(const float4*)(mkB + (size_t)c * HW + (m0 + mq * 4));
      Kt[mq * 4 + 0][c] = f2b(v.x);
      Kt[mq * 4 + 1][c] = f2b(v.y);
      Kt[mq * 4 + 2][c] = f2b(v.z);
      Kt[mq * 4 + 3][c] = f2b(v.w);
    }
#pragma unroll
    for (int i = 0; i < 4; ++i) {
      int f = i * 256 + tid;
      int cvr = f >> 3;
      int mq = f & 7;
      float4 v = *(const float4*)(mvB + (size_t)cvr * HW + (m0 + mq * 4));
      unsigned lo = (unsigned)f2b(v.x) | ((unsigned)f2b(v.y) << 16);
      unsigned hi2 = (unsigned)f2b(v.z) | ((unsigned)f2b(v.w) << 16);
      *(uint2*)&U.Vt[cvr][mq * 4] = make_uint2(lo, hi2);
    }
    __syncthreads();

    if (tid < 128) {
      int m = tid >> 2;
      int c0 = (tid & 3) * 16;
      bf16x8 a0 = *(const bf16x8*)&Kt[m][c0];
      bf16x8 a1 = *(const bf16x8*)&Kt[m][c0 + 8];
      float s = 0.f;
#pragma unroll
      for (int e = 0; e < 8; ++e) {
        float x = b2f((unsigned short)a0[e]);
        float y = b2f((unsigned short)a1[e]);
        s += x * x + y * y;
      }
      s += __shfl_xor(s, 1);
      s += __shfl_xor(s, 2);
      if ((tid & 3) == 0) asq[m] = s;
    }
    __syncthreads();

    bf16x8 af[2][2];
#pragma unroll
    for (int mt = 0; mt < 2; ++mt)
#pragma unroll
      for (int cs = 0; cs < 2; ++cs)
        af[mt][cs] = *(const bf16x8*)&Kt[mt * 16 + ln][cs * 32 + q * 8];

    float sv[2][2][4];
#pragma unroll
    for (int mt = 0; mt < 2; ++mt) {
      float4 aq = *(const float4*)&asq[mt * 16 + q * 4];
#pragma unroll
      for (int nt = 0; nt < 2; ++nt) {
        f32x4 d = {0.f, 0.f, 0.f, 0.f};
        d = __builtin_amdgcn_mfma_f32_16x16x32_bf16(af[mt][0], qf[nt][0], d, 0, 0, 0);
        d = __builtin_amdgcn_mfma_f32_16x16x32_bf16(af[mt][1], qf[nt][1], d, 0, 0, 0);
        sv[mt][nt][0] = (2.f * d[0] - aq.x) * 0.125f;
        sv[mt][nt][1] = (2.f * d[1] - aq.y) * 0.125f;
        sv[mt][nt][2] = (2.f * d[2] - aq.z) * 0.125f;
        sv[mt][nt][3] = (2.f * d[3] - aq.w) * 0.125f;
      }
    }

#pragma unroll
    for (int nt = 0; nt < 2; ++nt) {
      float tm = sv[0][nt][0];
#pragma unroll
      for (int mt = 0; mt < 2; ++mt)
#pragma unroll
        for (int r = 0; r < 4; ++r) tm = fmaxf(tm, sv[mt][nt][r]);
      tm = fmaxf(tm, __shfl_xor(tm, 16));
      tm = fmaxf(tm, __shfl_xor(tm, 32));
      float mnew = fmaxf(mrun[nt], tm);
      float sc = __expf(mrun[nt] - mnew);
      float ts = 0.f;
      unsigned short pb[2][4];
#pragma unroll
      for (int mt = 0; mt < 2; ++mt)
#pragma unroll
        for (int r = 0; r < 4; ++r) {
          float p = __expf(sv[mt][nt][r] - mnew);
          ts += p;
          pb[mt][r] = f2b(p);
        }
      ts += __shfl_xor(ts, 16);
      ts += __shfl_xor(ts, 32);
      lrun[nt] = lrun[nt] * sc + ts;
      mrun[nt] = mnew;
#pragma unroll
      for (int ct = 0; ct < 8; ++ct) {
        acc[ct][nt][0] *= sc; acc[ct][nt][1] *= sc;
        acc[ct][nt][2] *= sc; acc[ct][nt][3] *= sc;
      }
#pragma unroll
      for (int mt = 0; mt < 2; ++mt) {
        unsigned lo = (unsigned)pb[mt][0] | ((unsigned)pb[mt][1] << 16);
        unsigned hi2 = (unsigned)pb[mt][2] | ((unsigned)pb[mt][3] << 16);
        *(uint2*)&Pl[w][nt * 16 + ln][mt * 16 + q * 4] = make_uint2(lo, hi2);
      }
    }

    bf16x8 pf[2];
    pf[0] = *(const bf16x8*)&Pl[w][ln][q * 8];
    pf[1] = *(const bf16x8*)&Pl[w][16 + ln][q * 8];
#pragma unroll
    for (int ct = 0; ct < 8; ++ct) {
      bf16x8 vf = *(const bf16x8*)&U.Vt[ct * 16 + ln][q * 8];
      acc[ct][0] = __builtin_amdgcn_mfma_f32_16x16x32_bf16(vf, pf[0], acc[ct][0], 0, 0, 0);
      acc[ct][1] = __builtin_amdgcn_mfma_f32_16x16x32_bf16(vf, pf[1], acc[ct][1], 0, 0, 0);
    }
  }

#pragma unroll
  for (int nt = 0; nt < 2; ++nt) {
    float rl = 1.f / lrun[nt];
    int n = n0 + w * 32 + nt * 16 + ln;
#pragma unroll
    for (int ct = 0; ct < 8; ++ct) {
#pragma unroll
      for (int r = 0; r < 4; ++r) {
        int ch = cv0 + ct * 16 + q * 4 + r;
        out[((size_t)b * 1024 + ch) * HW + n] = acc[ct][nt][r] * rl;
      }
    }
  }
}

// concat tail: out[:, 512:1024, :, :] = qv
__global__ void qv_copy(const float4* __restrict__ qv, float4* __restrict__ out)
{
  size_t i = (size_t)blockIdx.x * blockDim.x + threadIdx.x;
  constexpr size_t TOT = (size_t)NB * CVAL * (HW / 4);
  if (i >= TOT) return;
  size_t n4  = i & (HW / 4 - 1);
  size_t cvb = i >> 10;
  size_t b   = cvb >> 9;
  size_t cv  = cvb & 511;
  out[((b * 1024) + 512 + cv) * (HW / 4) + n4] = qv[i];
}

extern "C" void kernel_launch(void* const* d_in, const int* in_sizes, int n_in,
                              void* d_out, int out_size, void* d_ws, size_t ws_size,
                              hipStream_t stream) {
  const float* mk = (const float*)d_in[0];
  const float* qk = (const float*)d_in[1];
  const float* mv = (const float*)d_in[2];
  const float* qv = (const float*)d_in[3];
  float* out = (float*)d_out;

  constexpr size_t KT   = (size_t)NB * HW * CK;            // ushort elems
  constexpr size_t MV8  = (size_t)NB * CVAL * HW;          // fp8 bytes
  constexpr size_t ASQ  = (size_t)NB * HW;
  constexpr size_t NEED = KT * 2 * 2 + MV8 + ASQ * 4;

  if (ws_size >= NEED) {
    unsigned short* kt  = (unsigned short*)d_ws;
    unsigned short* qtp = kt + KT;
    unsigned char*  mvs = (unsigned char*)(qtp + KT);
    float* aq = (float*)(mvs + MV8);
    prep_kt<<<dim3(HW / 256, NB), 256, 0, stream>>>(mk, kt, aq, 1);
    prep_kt<<<dim3(HW / 256, NB), 256, 0, stream>>>(qk, qtp, nullptr, 0);
    prep_mv8<<<(NB * 2 * 64 * 1024) / 256, 256, 0, stream>>>(mv, mvs);
    mr_flash10<<<dim3(HW / NT, CVAL / CVT, NB), 256, 0, stream>>>(kt, qtp, mvs, aq, out);
  } else {
    mr_flash<<<dim3(HW / NT, CVAL / 128, NB), 256, 0, stream>>>(mk, qk, mv, out);
  }

  constexpr int NCPY = NB * CVAL * (HW / 4);
  qv_copy<<<(NCPY + 255) / 256, 256, 0, stream>>>((const float4*)qv, (float4*)out);
}